// Round 3
// baseline (379.364 us; speedup 1.0000x reference)
//
#include <hip/hip_runtime.h>
#include <hip/hip_bf16.h>

typedef __attribute__((ext_vector_type(8))) short bf16x8;
typedef __attribute__((ext_vector_type(4))) float f32x4;

#define B_ 1024
#define T_ 256
#define C_ 384
#define H_ 64

__device__ __forceinline__ unsigned short f2bf(float f) {
  unsigned int u = __float_as_uint(f);
  return (unsigned short)((u + 0x7fffu + ((u >> 16) & 1u)) >> 16);
}

// ============================ NEW SPLIT PATH ============================
// wtp fragment-linear: wtp[((ks*12+nt)*64 + lane)*8 + i] =
//   bf16( W'[n = nt*16 + (lane&15)][k = ks*32 + (lane>>4)*8 + i] )
__global__ void pack_w_frag(const float* __restrict__ Wq, const float* __restrict__ Wk,
                            const float* __restrict__ Wv, unsigned short* __restrict__ wtp) {
  int id = blockIdx.x * 256 + threadIdx.x;
  if (id >= 144 * 512) return;
  int i = id & 7, lane = (id >> 3) & 63, f = id >> 9;
  int nt = f % 12, ks = f / 12;
  int n = nt * 16 + (lane & 15);
  int k = ks * 32 + (lane >> 4) * 8 + i;
  const float* W = (n < 64) ? Wq : ((n < 128) ? Wk : Wv);
  wtp[id] = f2bf(W[k * 64 + (n & 63)]);
}

// Q/K packed A/B-frag layout: qp[(((b*16+tile)*2+ks2)*64 + L)*8 + i] =
//   Q[b][tile*16 + (L&15)][ks2*32 + (L>>4)*8 + i]
// V packed B-frag (transposed): vp[(((b*4+nt)*8+ks)*64 + L)*8 + i] =
//   V[b][ks*32 + (L>>4)*8 + i][nt*16 + (L&15)]
__launch_bounds__(256, 4)
__global__ void qkv_kernel(const float* __restrict__ x, const float* __restrict__ cosp,
                           const float* __restrict__ sinp,
                           const unsigned short* __restrict__ wtp,
                           unsigned short* __restrict__ qp,
                           unsigned short* __restrict__ kp,
                           unsigned short* __restrict__ vp) {
  const int tid = threadIdx.x;
  const int w = tid >> 6;        // wave 0..3
  const int lane = tid & 63;
  const int l15 = lane & 15;
  const int lq = lane >> 4;
  const int bk = blockIdx.x;     // 0..2047
  const int b = bk >> 1, half = bk & 1;
  const int rt[2] = {half * 8 + w, half * 8 + 7 - w};

  const float* xb = x + (size_t)b * T_ * C_;

  f32x4 acc[2][12];
  #pragma unroll
  for (int i = 0; i < 2; ++i)
    #pragma unroll
    for (int nt = 0; nt < 12; ++nt) {
      f32x4 z = {0.f, 0.f, 0.f, 0.f};
      acc[i][nt] = z;
    }

  // depth-2 register prefetch of x
  float4 px[2][2][2];
  #pragma unroll
  for (int s = 0; s < 2; ++s)
    #pragma unroll
    for (int i = 0; i < 2; ++i) {
      const float* p = xb + (rt[i] * 16 + l15) * C_ + s * 32 + lq * 8;
      px[s][i][0] = *(const float4*)p;
      px[s][i][1] = *(const float4*)(p + 4);
    }

  #pragma unroll
  for (int ks = 0; ks < 12; ++ks) {
    const int cur = ks & 1;
    bf16x8 af[2];
    #pragma unroll
    for (int i = 0; i < 2; ++i) {
      bf16x8 a;
      a[0] = (short)f2bf(px[cur][i][0].x); a[1] = (short)f2bf(px[cur][i][0].y);
      a[2] = (short)f2bf(px[cur][i][0].z); a[3] = (short)f2bf(px[cur][i][0].w);
      a[4] = (short)f2bf(px[cur][i][1].x); a[5] = (short)f2bf(px[cur][i][1].y);
      a[6] = (short)f2bf(px[cur][i][1].z); a[7] = (short)f2bf(px[cur][i][1].w);
      af[i] = a;
    }
    // fragment-linear W loads: lane*16B, fully coalesced
    bf16x8 bfv[12];
    #pragma unroll
    for (int nt = 0; nt < 12; ++nt)
      bfv[nt] = *(const bf16x8*)(wtp + ((ks * 12 + nt) * 64 + lane) * 8);
    if (ks + 2 < 12) {
      #pragma unroll
      for (int i = 0; i < 2; ++i) {
        const float* p = xb + (rt[i] * 16 + l15) * C_ + (ks + 2) * 32 + lq * 8;
        px[cur][i][0] = *(const float4*)p;
        px[cur][i][1] = *(const float4*)(p + 4);
      }
    }
    #pragma unroll
    for (int nt = 0; nt < 12; ++nt)
      #pragma unroll
      for (int i = 0; i < 2; ++i)
        acc[i][nt] = __builtin_amdgcn_mfma_f32_16x16x32_bf16(af[i], bfv[nt], acc[i][nt], 0, 0, 0);
  }

  // RoPE on q (nt 0..3) and k (nt 4..7)
  #pragma unroll
  for (int i = 0; i < 2; ++i) {
    #pragma unroll
    for (int j = 0; j < 4; ++j) {
      int t = rt[i] * 16 + lq * 4 + j;
      #pragma unroll
      for (int h = 0; h < 2; ++h) {
        int c = h * 16 + l15;
        float cv = cosp[t * H_ + c];
        float sv = sinp[t * H_ + c];
        float a = acc[i][h][j], bb = acc[i][h + 2][j];
        acc[i][h][j]     = a * cv - bb * sv;
        acc[i][h + 2][j] = bb * cv + a * sv;
        float a2 = acc[i][4 + h][j], b2 = acc[i][6 + h][j];
        acc[i][4 + h][j] = a2 * cv - b2 * sv;
        acc[i][6 + h][j] = b2 * cv + a2 * sv;
      }
    }
  }

  // scatter-write packed fragments
  #pragma unroll
  for (int i = 0; i < 2; ++i) {
    const int tile = rt[i];
    #pragma unroll
    for (int j = 0; j < 4; ++j) {
      const int r = lq * 4 + j;  // row within tile
      #pragma unroll
      for (int nt = 0; nt < 4; ++nt) {
        // Q/K: L = ((nt&1)*2 + (l15>>3))*16 + r, i' = l15&7, ks2 = nt>>1
        size_t qa = ((((size_t)b * 16 + tile) * 2 + (nt >> 1)) * 64 +
                     ((nt & 1) * 2 + (l15 >> 3)) * 16 + r) * 8 + (l15 & 7);
        qp[qa] = f2bf(acc[i][nt][j]);
        kp[qa] = f2bf(acc[i][4 + nt][j]);
        // V: ks = tile>>1, L = ((tile&1)*2 + (r>>3))*16 + l15, i' = r&7
        size_t va = ((((size_t)b * 4 + nt) * 8 + (tile >> 1)) * 64 +
                     ((tile & 1) * 2 + (r >> 3)) * 16 + l15) * 8 + (r & 7);
        vp[va] = f2bf(acc[i][8 + nt][j]);
      }
    }
  }
}

__launch_bounds__(256, 4)
__global__ void attn_kernel(const unsigned short* __restrict__ qp,
                            const unsigned short* __restrict__ kp,
                            const unsigned short* __restrict__ vp,
                            float* __restrict__ out) {
  __shared__ unsigned short Plds[4 * 16 * 264];

  const int tid = threadIdx.x;
  const int w = tid >> 6;
  const int lane = tid & 63;
  const int l15 = lane & 15;
  const int lq = lane >> 4;
  const int bk = blockIdx.x;
  const int b = bk >> 1, half = bk & 1;
  const int rt2[2] = {half * 8 + w, half * 8 + 7 - w};

  unsigned short* Pw = Plds + w * 16 * 264;
  float* ob = out + (size_t)b * T_ * H_;

  #pragma unroll
  for (int i = 0; i < 2; ++i) {
    const int ti = rt2[i];
    const int t0 = ti * 16;

    bf16x8 aq[2];
    #pragma unroll
    for (int ks2 = 0; ks2 < 2; ++ks2)
      aq[ks2] = *(const bf16x8*)(qp + ((((size_t)b * 16 + ti) * 2 + ks2) * 64 + lane) * 8);

    f32x4 sacc[16];
    #pragma unroll
    for (int si = 0; si < 16; ++si) {
      f32x4 z = {0.f, 0.f, 0.f, 0.f};
      sacc[si] = z;
    }

    #pragma unroll
    for (int si = 0; si < 16; ++si) {
      if (si <= ti) {  // wave-uniform causal tile skip
        #pragma unroll
        for (int ks2 = 0; ks2 < 2; ++ks2) {
          bf16x8 bkf = *(const bf16x8*)(kp + ((((size_t)b * 16 + si) * 2 + ks2) * 64 + lane) * 8);
          sacc[si] = __builtin_amdgcn_mfma_f32_16x16x32_bf16(aq[ks2], bkf, sacc[si], 0, 0, 0);
        }
      }
    }

    // scale + causal mask
    int trow = t0 + lq * 4;
    #pragma unroll
    for (int si = 0; si < 16; ++si) {
      #pragma unroll
      for (int j = 0; j < 4; ++j) {
        float s = sacc[si][j] * 0.125f;
        if (si * 16 + l15 > trow + j) s = -1e30f;
        sacc[si][j] = s;
      }
    }

    // softmax per row (16-lane groups); P -> wave-private LDS
    float rl[4];
    #pragma unroll
    for (int j = 0; j < 4; ++j) {
      float mj = -1e30f;
      #pragma unroll
      for (int si = 0; si < 16; ++si) mj = fmaxf(mj, sacc[si][j]);
      #pragma unroll
      for (int d = 1; d < 16; d <<= 1) mj = fmaxf(mj, __shfl_xor(mj, d));
      float lj = 0.0f;
      #pragma unroll
      for (int si = 0; si < 16; ++si) {
        float p = __expf(sacc[si][j] - mj);
        lj += p;
        Pw[(lq * 4 + j) * 264 + si * 16 + l15] = f2bf(p);
      }
      #pragma unroll
      for (int d = 1; d < 16; d <<= 1) lj += __shfl_xor(lj, d);
      rl[j] = 1.0f / lj;
    }

    // PV
    f32x4 oacc[4];
    #pragma unroll
    for (int nt = 0; nt < 4; ++nt) {
      f32x4 z = {0.f, 0.f, 0.f, 0.f};
      oacc[nt] = z;
    }
    int nk = (t0 + 16 + 31) >> 5;
    for (int ks = 0; ks < nk; ++ks) {
      bf16x8 ap = *(const bf16x8*)&Pw[l15 * 264 + ks * 32 + lq * 8];
      #pragma unroll
      for (int nt = 0; nt < 4; ++nt) {
        bf16x8 bv = *(const bf16x8*)(vp + ((((size_t)b * 4 + nt) * 8 + ks) * 64 + lane) * 8);
        oacc[nt] = __builtin_amdgcn_mfma_f32_16x16x32_bf16(ap, bv, oacc[nt], 0, 0, 0);
      }
    }

    #pragma unroll
    for (int nt = 0; nt < 4; ++nt)
      #pragma unroll
      for (int j = 0; j < 4; ++j)
        ob[(t0 + lq * 4 + j) * H_ + nt * 16 + l15] = oacc[nt][j] * rl[j];
  }
}

// ============================ FALLBACK (round-2) PATH ============================
__global__ void pack_w_rm(const float* __restrict__ Wq, const float* __restrict__ Wk,
                          const float* __restrict__ Wv, unsigned short* __restrict__ wt) {
  int id = blockIdx.x * 256 + threadIdx.x;
  if (id >= 192 * 384) return;
  int n = id / 384, k = id % 384;
  const float* W = (n < 64) ? Wq : ((n < 128) ? Wk : Wv);
  wt[id] = f2bf(W[k * 64 + (n & 63)]);
}

__launch_bounds__(512, 2)
__global__ void head_fused(const float* __restrict__ x, const float* __restrict__ cosp,
                           const float* __restrict__ sinp,
                           const unsigned short* __restrict__ wt,
                           float* __restrict__ out) {
  __shared__ unsigned short Klds[256 * 72];
  __shared__ unsigned short Vlds[64 * 264];
  __shared__ unsigned short Plds[8 * 16 * 264];

  const int tid = threadIdx.x;
  const int w = tid >> 6;
  const int lane = tid & 63;
  const int l15 = lane & 15;
  const int lq = lane >> 4;
  const int b = blockIdx.x;

  const float* xb = x + (size_t)b * T_ * C_;
  const int rt[2] = {w, 15 - w};

  f32x4 acc[2][12];
  #pragma unroll
  for (int i = 0; i < 2; ++i)
    #pragma unroll
    for (int nt = 0; nt < 12; ++nt) {
      f32x4 z = {0.f, 0.f, 0.f, 0.f};
      acc[i][nt] = z;
    }

  float4 px[2][2][2];
  #pragma unroll
  for (int s = 0; s < 2; ++s)
    #pragma unroll
    for (int i = 0; i < 2; ++i) {
      const float* p = xb + (rt[i] * 16 + l15) * C_ + s * 32 + lq * 8;
      px[s][i][0] = *(const float4*)p;
      px[s][i][1] = *(const float4*)(p + 4);
    }

  #pragma unroll
  for (int ks = 0; ks < 12; ++ks) {
    const int cur = ks & 1;
    const int k0 = ks * 32 + lq * 8;
    bf16x8 af[2];
    #pragma unroll
    for (int i = 0; i < 2; ++i) {
      bf16x8 a;
      a[0] = (short)f2bf(px[cur][i][0].x); a[1] = (short)f2bf(px[cur][i][0].y);
      a[2] = (short)f2bf(px[cur][i][0].z); a[3] = (short)f2bf(px[cur][i][0].w);
      a[4] = (short)f2bf(px[cur][i][1].x); a[5] = (short)f2bf(px[cur][i][1].y);
      a[6] = (short)f2bf(px[cur][i][1].z); a[7] = (short)f2bf(px[cur][i][1].w);
      af[i] = a;
    }
    bf16x8 bfv[12];
    #pragma unroll
    for (int nt = 0; nt < 12; ++nt)
      bfv[nt] = *(const bf16x8*)(wt + (nt * 16 + l15) * C_ + k0);
    if (ks + 2 < 12) {
      #pragma unroll
      for (int i = 0; i < 2; ++i) {
        const float* p = xb + (rt[i] * 16 + l15) * C_ + (ks + 2) * 32 + lq * 8;
        px[cur][i][0] = *(const float4*)p;
        px[cur][i][1] = *(const float4*)(p + 4);
      }
    }
    #pragma unroll
    for (int nt = 0; nt < 12; ++nt)
      #pragma unroll
      for (int i = 0; i < 2; ++i)
        acc[i][nt] = __builtin_amdgcn_mfma_f32_16x16x32_bf16(af[i], bfv[nt], acc[i][nt], 0, 0, 0);
  }

  #pragma unroll
  for (int i = 0; i < 2; ++i) {
    #pragma unroll
    for (int j = 0; j < 4; ++j) {
      int t = rt[i] * 16 + lq * 4 + j;
      #pragma unroll
      for (int h = 0; h < 2; ++h) {
        int c = h * 16 + l15;
        float cv = cosp[t * H_ + c];
        float sv = sinp[t * H_ + c];
        float a = acc[i][h][j], bb = acc[i][h + 2][j];
        acc[i][h][j]     = a * cv - bb * sv;
        acc[i][h + 2][j] = bb * cv + a * sv;
        float a2 = acc[i][4 + h][j], b2 = acc[i][6 + h][j];
        acc[i][4 + h][j] = a2 * cv - b2 * sv;
        acc[i][6 + h][j] = b2 * cv + a2 * sv;
      }
    }
  }

  unsigned short* Pw = Plds + w * 16 * 264;
  #pragma unroll
  for (int i = 0; i < 2; ++i) {
    #pragma unroll
    for (int j = 0; j < 4; ++j) {
      int t = rt[i] * 16 + lq * 4 + j;
      int qr = i * 16 + lq * 4 + j;
      #pragma unroll
      for (int nt = 0; nt < 4; ++nt) {
        Pw[qr * 72 + nt * 16 + l15]    = f2bf(acc[i][nt][j]);
        Klds[t * 72 + nt * 16 + l15]   = f2bf(acc[i][4 + nt][j]);
        Vlds[(nt * 16 + l15) * 264 + t] = f2bf(acc[i][8 + nt][j]);
      }
    }
  }

  bf16x8 aq[2][2];
  #pragma unroll
  for (int i = 0; i < 2; ++i)
    #pragma unroll
    for (int ks2 = 0; ks2 < 2; ++ks2)
      aq[i][ks2] = *(const bf16x8*)&Pw[(i * 16 + l15) * 72 + ks2 * 32 + lq * 8];

  __syncthreads();

  float* ob = out + (size_t)b * T_ * H_;

  #pragma unroll
  for (int i = 0; i < 2; ++i) {
    const int ti = rt[i];
    const int t0 = ti * 16;

    f32x4 sacc[16];
    #pragma unroll
    for (int si = 0; si < 16; ++si) {
      f32x4 z = {0.f, 0.f, 0.f, 0.f};
      sacc[si] = z;
    }
    #pragma unroll
    for (int si = 0; si < 16; ++si) {
      if (si <= ti) {
        #pragma unroll
        for (int ks2 = 0; ks2 < 2; ++ks2) {
          bf16x8 bkf = *(const bf16x8*)&Klds[(si * 16 + l15) * 72 + ks2 * 32 + lq * 8];
          sacc[si] = __builtin_amdgcn_mfma_f32_16x16x32_bf16(aq[i][ks2], bkf, sacc[si], 0, 0, 0);
        }
      }
    }
    int trow = t0 + lq * 4;
    #pragma unroll
    for (int si = 0; si < 16; ++si) {
      #pragma unroll
      for (int j = 0; j < 4; ++j) {
        float s = sacc[si][j] * 0.125f;
        if (si * 16 + l15 > trow + j) s = -1e30f;
        sacc[si][j] = s;
      }
    }
    float rl[4];
    #pragma unroll
    for (int j = 0; j < 4; ++j) {
      float mj = -1e30f;
      #pragma unroll
      for (int si = 0; si < 16; ++si) mj = fmaxf(mj, sacc[si][j]);
      #pragma unroll
      for (int d = 1; d < 16; d <<= 1) mj = fmaxf(mj, __shfl_xor(mj, d));
      float lj = 0.0f;
      #pragma unroll
      for (int si = 0; si < 16; ++si) {
        float p = __expf(sacc[si][j] - mj);
        lj += p;
        Pw[(lq * 4 + j) * 264 + si * 16 + l15] = f2bf(p);
      }
      #pragma unroll
      for (int d = 1; d < 16; d <<= 1) lj += __shfl_xor(lj, d);
      rl[j] = 1.0f / lj;
    }
    f32x4 oacc[4];
    #pragma unroll
    for (int nt = 0; nt < 4; ++nt) {
      f32x4 z = {0.f, 0.f, 0.f, 0.f};
      oacc[nt] = z;
    }
    int nk = (t0 + 16 + 31) >> 5;
    for (int ks2 = 0; ks2 < nk; ++ks2) {
      bf16x8 ap = *(const bf16x8*)&Pw[l15 * 264 + ks2 * 32 + lq * 8];
      #pragma unroll
      for (int nt = 0; nt < 4; ++nt) {
        bf16x8 bv = *(const bf16x8*)&Vlds[(nt * 16 + l15) * 264 + ks2 * 32 + lq * 8];
        oacc[nt] = __builtin_amdgcn_mfma_f32_16x16x32_bf16(ap, bv, oacc[nt], 0, 0, 0);
      }
    }
    #pragma unroll
    for (int nt = 0; nt < 4; ++nt)
      #pragma unroll
      for (int j = 0; j < 4; ++j)
        ob[(t0 + lq * 4 + j) * H_ + nt * 16 + l15] = oacc[nt][j] * rl[j];
  }
}

extern "C" void kernel_launch(void* const* d_in, const int* in_sizes, int n_in,
                              void* d_out, int out_size, void* d_ws, size_t ws_size,
                              hipStream_t stream) {
  const float* x    = (const float*)d_in[0];
  const float* cosp = (const float*)d_in[1];
  const float* sinp = (const float*)d_in[2];
  const float* Wq   = (const float*)d_in[3];
  const float* Wk   = (const float*)d_in[4];
  const float* Wv   = (const float*)d_in[5];
  float* out = (float*)d_out;

  const size_t wtp_bytes = 144 * 512 * 2;                 // 147456
  const size_t frag_elems = (size_t)B_ * 16 * 2 * 64 * 8; // 16777216 each
  const size_t need = wtp_bytes + 3 * frag_elems * 2;     // ~100.8 MB

  if (ws_size >= need) {
    unsigned short* wtp = (unsigned short*)d_ws;
    unsigned short* qp = (unsigned short*)((char*)d_ws + wtp_bytes);
    unsigned short* kp = qp + frag_elems;
    unsigned short* vp = kp + frag_elems;
    pack_w_frag<<<288, 256, 0, stream>>>(Wq, Wk, Wv, wtp);
    qkv_kernel<<<2048, 256, 0, stream>>>(x, cosp, sinp, wtp, qp, kp, vp);
    attn_kernel<<<2048, 256, 0, stream>>>(qp, kp, vp, out);
  } else {
    unsigned short* wt = (unsigned short*)d_ws;  // 147 KB row-major
    pack_w_rm<<<288, 256, 0, stream>>>(Wq, Wk, Wv, wt);
    head_fused<<<B_, 512, 0, stream>>>(x, cosp, sinp, wt, out);
  }
}

// Round 4
// 247.489 us; speedup vs baseline: 1.5329x; 1.5329x over previous
//
#include <hip/hip_runtime.h>
#include <hip/hip_bf16.h>

typedef __attribute__((ext_vector_type(8))) short bf16x8;
typedef __attribute__((ext_vector_type(4))) float f32x4;

#define B_ 1024
#define T_ 256
#define C_ 384
#define H_ 64

static __device__ __forceinline__ unsigned short f2bf(float f) {
  unsigned int u = __float_as_uint(f);
  return (unsigned short)((u + 0x7fffu + ((u >> 16) & 1u)) >> 16);
}

static __device__ __forceinline__ void glds16(const void* g, void* l) {
  __builtin_amdgcn_global_load_lds((const __attribute__((address_space(1))) void*)g,
                                   (__attribute__((address_space(3))) void*)l, 16, 0, 0);
}

static __device__ __forceinline__ bf16x8 cvt8(float4 a, float4 b) {
  union { __hip_bfloat162 h[4]; bf16x8 v; } u;
  u.h[0] = __float22bfloat162_rn(make_float2(a.x, a.y));
  u.h[1] = __float22bfloat162_rn(make_float2(a.z, a.w));
  u.h[2] = __float22bfloat162_rn(make_float2(b.x, b.y));
  u.h[3] = __float22bfloat162_rn(make_float2(b.z, b.w));
  return u.v;
}

// wtp fragment-linear: wtp[((ks*12+nt)*64 + lane)*8 + i] =
//   bf16( W'[n = nt*16 + (lane&15)][k = ks*32 + (lane>>4)*8 + i] )
__global__ void pack_w_frag(const float* __restrict__ Wq, const float* __restrict__ Wk,
                            const float* __restrict__ Wv, unsigned short* __restrict__ wtp) {
  int id = blockIdx.x * 256 + threadIdx.x;
  if (id >= 144 * 512) return;
  int i = id & 7, lane = (id >> 3) & 63, f = id >> 9;
  int nt = f % 12, ks = f / 12;
  int n = nt * 16 + (lane & 15);
  int k = ks * 32 + (lane >> 4) * 8 + i;
  const float* W = (n < 64) ? Wq : ((n < 128) ? Wk : Wv);
  wtp[id] = f2bf(W[k * 64 + (n & 63)]);
}

// Q/K packed frag layout: qp[(((b*16+tile)*2+ks2)*64 + L)*8 + i] =
//   Q[b][tile*16 + (L&15)][ks2*32 + (L>>4)*8 + i]
// V packed frag (transposed): vp[(((b*4+nt)*8+ks)*64 + L)*8 + i] =
//   V[b][ks*32 + (L>>4)*8 + i][nt*16 + (L&15)]
__launch_bounds__(256, 2)
__global__ void qkv_kernel(const float* __restrict__ x, const float* __restrict__ cosp,
                           const float* __restrict__ sinp,
                           const unsigned short* __restrict__ wtp,
                           unsigned short* __restrict__ qp,
                           unsigned short* __restrict__ kp,
                           unsigned short* __restrict__ vp) {
  // 8 KB per wave: double-buffered x chunk [2][32 rows][128 B], later reused
  // as the D-frag -> store staging tile. Entirely wave-local: NO barriers.
  __shared__ __align__(16) char smem[4][8192];

  const int tid = threadIdx.x;
  const int w = tid >> 6;
  const int lane = tid & 63;
  const int l15 = lane & 15;
  const int lq = lane >> 4;
  const int bk = blockIdx.x;
  const int b = bk >> 1, half = bk & 1;
  const int tg0 = half * 8 + 2 * w;     // wave owns global tiles tg0, tg0+1
  const int row0 = tg0 * 16;            // 32 adjacent rows

  const float* xb = x + (size_t)b * T_ * C_;
  char* wbuf = smem[w];

  // stage x chunk ks (32 rows x 32 floats) into buffer hb, source pre-XOR-swizzled
  auto stage = [&](int ks, int hb) {
    char* dst = wbuf + hb * 4096;
    const int rl = lane >> 3;   // 0..7
    const int cg = lane & 7;
    #pragma unroll
    for (int s = 0; s < 4; ++s) {
      int row = s * 8 + rl;
      int cb = (cg * 16) ^ ((row & 7) << 4);
      const char* src = (const char*)(xb + (size_t)(row0 + row) * C_ + ks * 32) + cb;
      glds16(src, dst + s * 1024);   // dest wave-uniform; HW scatters lane*16
    }
  };

  f32x4 acc[2][12];
  #pragma unroll
  for (int i = 0; i < 2; ++i)
    #pragma unroll
    for (int nt = 0; nt < 12; ++nt) {
      f32x4 z = {0.f, 0.f, 0.f, 0.f};
      acc[i][nt] = z;
    }

  stage(0, 0);

  #pragma unroll
  for (int ks = 0; ks < 12; ++ks) {
    const int cur = ks & 1;
    // stage(ks) complete (only those loads are outstanding here)
    asm volatile("s_waitcnt vmcnt(0)" ::: "memory");

    // B-fragment loads first (older than the next stage -> counted vmcnt works)
    bf16x8 bfv[12];
    #pragma unroll
    for (int nt = 0; nt < 12; ++nt)
      bfv[nt] = *(const bf16x8*)(wtp + ((size_t)(ks * 12 + nt) * 64 + lane) * 8);

    if (ks + 1 < 12) stage(ks + 1, cur ^ 1);

    // A-frags from LDS (XOR-swizzled), convert to bf16
    const char* cbuf = wbuf + cur * 4096;
    const int sw = (l15 & 7) << 4;
    bf16x8 af[2];
    #pragma unroll
    for (int i = 0; i < 2; ++i) {
      const char* rp = cbuf + (i * 16 + l15) * 128;
      float4 f0 = *(const float4*)(rp + ((lq * 32) ^ sw));
      float4 f1 = *(const float4*)(rp + ((lq * 32 + 16) ^ sw));
      af[i] = cvt8(f0, f1);
    }

    #pragma unroll
    for (int nt = 0; nt < 12; ++nt)
      #pragma unroll
      for (int i = 0; i < 2; ++i)
        acc[i][nt] = __builtin_amdgcn_mfma_f32_16x16x32_bf16(af[i], bfv[nt], acc[i][nt], 0, 0, 0);
  }

  // ---------------- RoPE on q (nt 0..3) and k (nt 4..7)
  #pragma unroll
  for (int i = 0; i < 2; ++i) {
    #pragma unroll
    for (int j = 0; j < 4; ++j) {
      int t = (tg0 + i) * 16 + lq * 4 + j;
      #pragma unroll
      for (int h = 0; h < 2; ++h) {
        int c = h * 16 + l15;
        float cv = cosp[t * H_ + c];
        float sv = sinp[t * H_ + c];
        float a = acc[i][h][j], bb = acc[i][h + 2][j];
        acc[i][h][j]     = a * cv - bb * sv;
        acc[i][h + 2][j] = bb * cv + a * sv;
        float a2 = acc[i][4 + h][j], b2 = acc[i][6 + h][j];
        acc[i][4 + h][j] = a2 * cv - b2 * sv;
        acc[i][6 + h][j] = b2 * cv + a2 * sv;
      }
    }
  }

  // ---------------- staged, fully-coalesced frag writeout (wave-local LDS reuse)
  unsigned short* st = (unsigned short*)wbuf;

  // Q: stage [2 tiles][16 rows][72] then store 1KB frag lines
  #pragma unroll
  for (int i = 0; i < 2; ++i)
    #pragma unroll
    for (int nt = 0; nt < 4; ++nt)
      #pragma unroll
      for (int j = 0; j < 4; ++j)
        st[i * 1152 + (lq * 4 + j) * 72 + nt * 16 + l15] = f2bf(acc[i][nt][j]);
  #pragma unroll
  for (int i = 0; i < 2; ++i)
    #pragma unroll
    for (int ks2 = 0; ks2 < 2; ++ks2) {
      bf16x8 fr = *(const bf16x8*)&st[i * 1152 + l15 * 72 + ks2 * 32 + lq * 8];
      *(bf16x8*)(qp + ((((size_t)b * 16 + tg0 + i) * 2 + ks2) * 64 + lane) * 8) = fr;
    }

  // K: same staging region (compiler inserts WAR lgkm waits)
  #pragma unroll
  for (int i = 0; i < 2; ++i)
    #pragma unroll
    for (int nt = 0; nt < 4; ++nt)
      #pragma unroll
      for (int j = 0; j < 4; ++j)
        st[i * 1152 + (lq * 4 + j) * 72 + nt * 16 + l15] = f2bf(acc[i][4 + nt][j]);
  #pragma unroll
  for (int i = 0; i < 2; ++i)
    #pragma unroll
    for (int ks2 = 0; ks2 < 2; ++ks2) {
      bf16x8 fr = *(const bf16x8*)&st[i * 1152 + l15 * 72 + ks2 * 32 + lq * 8];
      *(bf16x8*)(kp + ((((size_t)b * 16 + tg0 + i) * 2 + ks2) * 64 + lane) * 8) = fr;
    }

  // V: transposed staging Vt[64 h][40] (32 t + pad), then frag lines
  #pragma unroll
  for (int i = 0; i < 2; ++i)
    #pragma unroll
    for (int nt = 0; nt < 4; ++nt)
      #pragma unroll
      for (int j = 0; j < 4; ++j)
        st[(nt * 16 + l15) * 40 + i * 16 + lq * 4 + j] = f2bf(acc[i][8 + nt][j]);
  {
    const int ksg = half * 4 + w;   // global 32-row k-index of this wave
    #pragma unroll
    for (int nt = 0; nt < 4; ++nt) {
      bf16x8 fr = *(const bf16x8*)&st[(nt * 16 + l15) * 40 + lq * 8];
      *(bf16x8*)(vp + ((((size_t)b * 4 + nt) * 8 + ksg) * 64 + lane) * 8) = fr;
    }
  }
}

__launch_bounds__(256, 4)
__global__ void attn_kernel(const unsigned short* __restrict__ qp,
                            const unsigned short* __restrict__ kp,
                            const unsigned short* __restrict__ vp,
                            float* __restrict__ out) {
  __shared__ unsigned short Plds[4 * 16 * 264];

  const int tid = threadIdx.x;
  const int w = tid >> 6;
  const int lane = tid & 63;
  const int l15 = lane & 15;
  const int lq = lane >> 4;
  const int bk = blockIdx.x;
  const int b = bk >> 1, half = bk & 1;
  const int rt2[2] = {half * 8 + w, half * 8 + 7 - w};

  unsigned short* Pw = Plds + w * 16 * 264;
  float* ob = out + (size_t)b * T_ * H_;

  #pragma unroll
  for (int i = 0; i < 2; ++i) {
    const int ti = rt2[i];
    const int t0 = ti * 16;

    bf16x8 aq[2];
    #pragma unroll
    for (int ks2 = 0; ks2 < 2; ++ks2)
      aq[ks2] = *(const bf16x8*)(qp + ((((size_t)b * 16 + ti) * 2 + ks2) * 64 + lane) * 8);

    f32x4 sacc[16];
    #pragma unroll
    for (int si = 0; si < 16; ++si) {
      f32x4 z = {0.f, 0.f, 0.f, 0.f};
      sacc[si] = z;
    }

    #pragma unroll
    for (int si = 0; si < 16; ++si) {
      if (si <= ti) {  // wave-uniform causal tile skip
        #pragma unroll
        for (int ks2 = 0; ks2 < 2; ++ks2) {
          bf16x8 bkf = *(const bf16x8*)(kp + ((((size_t)b * 16 + si) * 2 + ks2) * 64 + lane) * 8);
          sacc[si] = __builtin_amdgcn_mfma_f32_16x16x32_bf16(aq[ks2], bkf, sacc[si], 0, 0, 0);
        }
      }
    }

    // scale + causal mask
    int trow = t0 + lq * 4;
    #pragma unroll
    for (int si = 0; si < 16; ++si) {
      #pragma unroll
      for (int j = 0; j < 4; ++j) {
        float s = sacc[si][j] * 0.125f;
        if (si * 16 + l15 > trow + j) s = -1e30f;
        sacc[si][j] = s;
      }
    }

    // softmax per row (16-lane groups); P -> wave-private LDS
    float rl[4];
    #pragma unroll
    for (int j = 0; j < 4; ++j) {
      float mj = -1e30f;
      #pragma unroll
      for (int si = 0; si < 16; ++si) mj = fmaxf(mj, sacc[si][j]);
      #pragma unroll
      for (int d = 1; d < 16; d <<= 1) mj = fmaxf(mj, __shfl_xor(mj, d));
      float lj = 0.0f;
      #pragma unroll
      for (int si = 0; si < 16; ++si) {
        float p = __expf(sacc[si][j] - mj);
        lj += p;
        Pw[(lq * 4 + j) * 264 + si * 16 + l15] = f2bf(p);
      }
      #pragma unroll
      for (int d = 1; d < 16; d <<= 1) lj += __shfl_xor(lj, d);
      rl[j] = 1.0f / lj;
    }

    // PV
    f32x4 oacc[4];
    #pragma unroll
    for (int nt = 0; nt < 4; ++nt) {
      f32x4 z = {0.f, 0.f, 0.f, 0.f};
      oacc[nt] = z;
    }
    int nk = (t0 + 16 + 31) >> 5;
    for (int ks = 0; ks < nk; ++ks) {
      bf16x8 ap = *(const bf16x8*)&Pw[l15 * 264 + ks * 32 + lq * 8];
      #pragma unroll
      for (int nt = 0; nt < 4; ++nt) {
        bf16x8 bv = *(const bf16x8*)(vp + ((((size_t)b * 4 + nt) * 8 + ks) * 64 + lane) * 8);
        oacc[nt] = __builtin_amdgcn_mfma_f32_16x16x32_bf16(ap, bv, oacc[nt], 0, 0, 0);
      }
    }

    #pragma unroll
    for (int nt = 0; nt < 4; ++nt)
      #pragma unroll
      for (int j = 0; j < 4; ++j)
        ob[(t0 + lq * 4 + j) * H_ + nt * 16 + l15] = oacc[nt][j] * rl[j];
  }
}

// ============================ FALLBACK (round-2) PATH ============================
__global__ void pack_w_rm(const float* __restrict__ Wq, const float* __restrict__ Wk,
                          const float* __restrict__ Wv, unsigned short* __restrict__ wt) {
  int id = blockIdx.x * 256 + threadIdx.x;
  if (id >= 192 * 384) return;
  int n = id / 384, k = id % 384;
  const float* W = (n < 64) ? Wq : ((n < 128) ? Wk : Wv);
  wt[id] = f2bf(W[k * 64 + (n & 63)]);
}

__launch_bounds__(512, 2)
__global__ void head_fused(const float* __restrict__ x, const float* __restrict__ cosp,
                           const float* __restrict__ sinp,
                           const unsigned short* __restrict__ wt,
                           float* __restrict__ out) {
  __shared__ unsigned short Klds[256 * 72];
  __shared__ unsigned short Vlds[64 * 264];
  __shared__ unsigned short Plds[8 * 16 * 264];

  const int tid = threadIdx.x;
  const int w = tid >> 6;
  const int lane = tid & 63;
  const int l15 = lane & 15;
  const int lq = lane >> 4;
  const int b = blockIdx.x;

  const float* xb = x + (size_t)b * T_ * C_;
  const int rt[2] = {w, 15 - w};

  f32x4 acc[2][12];
  #pragma unroll
  for (int i = 0; i < 2; ++i)
    #pragma unroll
    for (int nt = 0; nt < 12; ++nt) {
      f32x4 z = {0.f, 0.f, 0.f, 0.f};
      acc[i][nt] = z;
    }

  float4 px[2][2][2];
  #pragma unroll
  for (int s = 0; s < 2; ++s)
    #pragma unroll
    for (int i = 0; i < 2; ++i) {
      const float* p = xb + (rt[i] * 16 + l15) * C_ + s * 32 + lq * 8;
      px[s][i][0] = *(const float4*)p;
      px[s][i][1] = *(const float4*)(p + 4);
    }

  #pragma unroll
  for (int ks = 0; ks < 12; ++ks) {
    const int cur = ks & 1;
    const int k0 = ks * 32 + lq * 8;
    bf16x8 af[2];
    #pragma unroll
    for (int i = 0; i < 2; ++i) af[i] = cvt8(px[cur][i][0], px[cur][i][1]);
    bf16x8 bfv[12];
    #pragma unroll
    for (int nt = 0; nt < 12; ++nt)
      bfv[nt] = *(const bf16x8*)(wt + (nt * 16 + l15) * C_ + k0);
    if (ks + 2 < 12) {
      #pragma unroll
      for (int i = 0; i < 2; ++i) {
        const float* p = xb + (rt[i] * 16 + l15) * C_ + (ks + 2) * 32 + lq * 8;
        px[cur][i][0] = *(const float4*)p;
        px[cur][i][1] = *(const float4*)(p + 4);
      }
    }
    #pragma unroll
    for (int nt = 0; nt < 12; ++nt)
      #pragma unroll
      for (int i = 0; i < 2; ++i)
        acc[i][nt] = __builtin_amdgcn_mfma_f32_16x16x32_bf16(af[i], bfv[nt], acc[i][nt], 0, 0, 0);
  }

  #pragma unroll
  for (int i = 0; i < 2; ++i) {
    #pragma unroll
    for (int j = 0; j < 4; ++j) {
      int t = rt[i] * 16 + lq * 4 + j;
      #pragma unroll
      for (int h = 0; h < 2; ++h) {
        int c = h * 16 + l15;
        float cv = cosp[t * H_ + c];
        float sv = sinp[t * H_ + c];
        float a = acc[i][h][j], bb = acc[i][h + 2][j];
        acc[i][h][j]     = a * cv - bb * sv;
        acc[i][h + 2][j] = bb * cv + a * sv;
        float a2 = acc[i][4 + h][j], b2 = acc[i][6 + h][j];
        acc[i][4 + h][j] = a2 * cv - b2 * sv;
        acc[i][6 + h][j] = b2 * cv + a2 * sv;
      }
    }
  }

  unsigned short* Pw = Plds + w * 16 * 264;
  #pragma unroll
  for (int i = 0; i < 2; ++i) {
    #pragma unroll
    for (int j = 0; j < 4; ++j) {
      int t = rt[i] * 16 + lq * 4 + j;
      int qr = i * 16 + lq * 4 + j;
      #pragma unroll
      for (int nt = 0; nt < 4; ++nt) {
        Pw[qr * 72 + nt * 16 + l15]    = f2bf(acc[i][nt][j]);
        Klds[t * 72 + nt * 16 + l15]   = f2bf(acc[i][4 + nt][j]);
        Vlds[(nt * 16 + l15) * 264 + t] = f2bf(acc[i][8 + nt][j]);
      }
    }
  }

  bf16x8 aq[2][2];
  #pragma unroll
  for (int i = 0; i < 2; ++i)
    #pragma unroll
    for (int ks2 = 0; ks2 < 2; ++ks2)
      aq[i][ks2] = *(const bf16x8*)&Pw[(i * 16 + l15) * 72 + ks2 * 32 + lq * 8];

  __syncthreads();

  float* ob = out + (size_t)b * T_ * H_;

  #pragma unroll
  for (int i = 0; i < 2; ++i) {
    const int ti = rt[i];
    const int t0 = ti * 16;

    f32x4 sacc[16];
    #pragma unroll
    for (int si = 0; si < 16; ++si) {
      f32x4 z = {0.f, 0.f, 0.f, 0.f};
      sacc[si] = z;
    }
    #pragma unroll
    for (int si = 0; si < 16; ++si) {
      if (si <= ti) {
        #pragma unroll
        for (int ks2 = 0; ks2 < 2; ++ks2) {
          bf16x8 bkf = *(const bf16x8*)&Klds[(si * 16 + l15) * 72 + ks2 * 32 + lq * 8];
          sacc[si] = __builtin_amdgcn_mfma_f32_16x16x32_bf16(aq[i][ks2], bkf, sacc[si], 0, 0, 0);
        }
      }
    }
    int trow = t0 + lq * 4;
    #pragma unroll
    for (int si = 0; si < 16; ++si) {
      #pragma unroll
      for (int j = 0; j < 4; ++j) {
        float s = sacc[si][j] * 0.125f;
        if (si * 16 + l15 > trow + j) s = -1e30f;
        sacc[si][j] = s;
      }
    }
    float rl[4];
    #pragma unroll
    for (int j = 0; j < 4; ++j) {
      float mj = -1e30f;
      #pragma unroll
      for (int si = 0; si < 16; ++si) mj = fmaxf(mj, sacc[si][j]);
      #pragma unroll
      for (int d = 1; d < 16; d <<= 1) mj = fmaxf(mj, __shfl_xor(mj, d));
      float lj = 0.0f;
      #pragma unroll
      for (int si = 0; si < 16; ++si) {
        float p = __expf(sacc[si][j] - mj);
        lj += p;
        Pw[(lq * 4 + j) * 264 + si * 16 + l15] = f2bf(p);
      }
      #pragma unroll
      for (int d = 1; d < 16; d <<= 1) lj += __shfl_xor(lj, d);
      rl[j] = 1.0f / lj;
    }
    f32x4 oacc[4];
    #pragma unroll
    for (int nt = 0; nt < 4; ++nt) {
      f32x4 z = {0.f, 0.f, 0.f, 0.f};
      oacc[nt] = z;
    }
    int nk = (t0 + 16 + 31) >> 5;
    for (int ks2 = 0; ks2 < nk; ++ks2) {
      bf16x8 ap = *(const bf16x8*)&Pw[l15 * 264 + ks2 * 32 + lq * 8];
      #pragma unroll
      for (int nt = 0; nt < 4; ++nt) {
        bf16x8 bv = *(const bf16x8*)&Vlds[(nt * 16 + l15) * 264 + ks2 * 32 + lq * 8];
        oacc[nt] = __builtin_amdgcn_mfma_f32_16x16x32_bf16(ap, bv, oacc[nt], 0, 0, 0);
      }
    }
    #pragma unroll
    for (int nt = 0; nt < 4; ++nt)
      #pragma unroll
      for (int j = 0; j < 4; ++j)
        ob[(t0 + lq * 4 + j) * H_ + nt * 16 + l15] = oacc[nt][j] * rl[j];
  }
}

extern "C" void kernel_launch(void* const* d_in, const int* in_sizes, int n_in,
                              void* d_out, int out_size, void* d_ws, size_t ws_size,
                              hipStream_t stream) {
  const float* x    = (const float*)d_in[0];
  const float* cosp = (const float*)d_in[1];
  const float* sinp = (const float*)d_in[2];
  const float* Wq   = (const float*)d_in[3];
  const float* Wk   = (const float*)d_in[4];
  const float* Wv   = (const float*)d_in[5];
  float* out = (float*)d_out;

  const size_t wtp_bytes = 144 * 512 * 2;                 // 147456
  const size_t frag_elems = (size_t)B_ * 16 * 2 * 64 * 8; // 16777216 each
  const size_t need = wtp_bytes + 3 * frag_elems * 2;     // ~100.8 MB

  if (ws_size >= need) {
    unsigned short* wtp = (unsigned short*)d_ws;
    unsigned short* qp = (unsigned short*)((char*)d_ws + wtp_bytes);
    unsigned short* kp = qp + frag_elems;
    unsigned short* vp = kp + frag_elems;
    pack_w_frag<<<288, 256, 0, stream>>>(Wq, Wk, Wv, wtp);
    qkv_kernel<<<2048, 256, 0, stream>>>(x, cosp, sinp, wtp, qp, kp, vp);
    attn_kernel<<<2048, 256, 0, stream>>>(qp, kp, vp, out);
  } else {
    unsigned short* wt = (unsigned short*)d_ws;
    pack_w_rm<<<288, 256, 0, stream>>>(Wq, Wk, Wv, wt);
    head_fused<<<B_, 512, 0, stream>>>(x, cosp, sinp, wt, out);
  }
}